// Round 1
// baseline (492.434 us; speedup 1.0000x reference)
//
#include <hip/hip_runtime.h>

// LSTMForecaster: B=4096, T=512, D=1, H=64, 2 layers + FC(64->1).
// R17 = R16 structure + FUSED single-wait sync path.
//   Evidence: per-step 2306 cyc vs ~870 issue cyc/SIMD -> ~1400 sync exposure.
//   Each wave did TWO serialized spin-waits/step; each is a ds_read->lgkm->cmp
//   round (~130cy fast path, +64cy sleep quantum slow path), and for L1 both
//   sit inside the h1 self-recurrence chain. Changes:
//     1. One fused wait/step: all flag loads issued together, one condition.
//     2. L0 precomputes x-proj FMAs while flag loads are in flight.
//     3. Double-poll per s_sleep(1) -> halves detect quantization.
//     4. setprio(1) compute / setprio(0) spin (role-split arbitration).
//     5. L1 issues all 4 h ds_reads right after the single wait.
//   Everything else byte-identical to R16: 12 waves (4 L0 x 16u, 8 L1 x 8u),
//   single-bf16 weights+h, h0 ring 8 / h1 ring 2, exp2-folded gate scales,
//   packed cells. If FAIL/regress: revert to R16 (492us).

#define TT 512
#define HH 64
#define NB 16
#define XP 516

typedef __bf16 bf16_t;
typedef bf16_t bf16x8 __attribute__((ext_vector_type(8)));
typedef float  f32x4  __attribute__((ext_vector_type(4)));
typedef float  f32x2  __attribute__((ext_vector_type(2)));

#define MFMA(A, B, C) __builtin_amdgcn_mfma_f32_16x16x32_bf16((A), (B), (C), 0, 0, 0)
#define RCPF(x) __builtin_amdgcn_rcpf(x)

#if __has_builtin(__builtin_amdgcn_exp2f)
#define EXP2F(x) __builtin_amdgcn_exp2f(x)
#else
__device__ __forceinline__ float EXP2F(float x) {
    float r;
    asm volatile("v_exp_f32 %0, %1" : "=v"(r) : "v"(x));
    return r;
}
#endif

#define SC_IFO (-1.4426950408889634f)   // -log2(e)
#define SC_G   ( 2.8853900817779268f)   // +2*log2(e)

__device__ __forceinline__ unsigned short f32_to_bf16_rne(float f) {
    unsigned int u = __builtin_bit_cast(unsigned int, f);
    unsigned int r = u + 0x7fffu + ((u >> 16) & 1u);
    return (unsigned short)(r >> 16);
}
__device__ __forceinline__ bf16_t bits_to_bf16(unsigned short u) {
    return __builtin_bit_cast(bf16_t, u);
}
// single-term weight frag with per-row scale folded in (RNE)
__device__ __forceinline__ void build_frag_scaled(const float* __restrict__ p, float sc,
                                                  bf16x8& w) {
    const float4 a = *(const float4*)p;
    const float4 b = *(const float4*)(p + 4);
    float v[8] = {a.x, a.y, a.z, a.w, b.x, b.y, b.z, b.w};
#pragma unroll
    for (int jj = 0; jj < 8; ++jj)
        w[jj] = bits_to_bf16(f32_to_bf16_rne(v[jj] * sc));
}

__device__ __forceinline__ f32x2 exp2v(f32x2 v) {
    f32x2 r; r[0] = EXP2F(v[0]); r[1] = EXP2F(v[1]); return r;
}
__device__ __forceinline__ f32x2 rcpv(f32x2 v) {
    f32x2 r; r[0] = RCPF(v[0]); r[1] = RCPF(v[1]); return r;
}
// Two cells on PRE-SCALED gates (is,fs,os scaled -log2e; gs scaled +2log2e).
__device__ __forceinline__ f32x2 cell2(const f32x4 a0, const f32x4 a1, f32x2* c) {
    f32x2 is = {a0[0], a1[0]}, fs = {a0[1], a1[1]};
    f32x2 gs = {a0[2], a1[2]}, os = {a0[3], a1[3]};
    const f32x2 pf = exp2v(fs);
    const f32x2 fg = rcpv(1.0f + pf);
    const f32x2 pi = exp2v(is);
    const f32x2 e2 = exp2v(gs);
    const f32x2 z  = (e2 - 1.0f) * rcpv((1.0f + pi) * (1.0f + e2));
    *c = fg * (*c) + z;
    const f32x2 po  = exp2v(os);
    const f32x2 e2c = exp2v((*c) * SC_G);
    return (e2c - 1.0f) * rcpv((1.0f + po) * (1.0f + e2c));
}

__device__ __forceinline__ int imin2(int a, int b) { return a < b ? a : b; }
__device__ __forceinline__ int min4of(const int* f) {
    const int4 v = *(const int4*)f;
    return imin2(imin2(v.x, v.y), imin2(v.z, v.w));
}
__device__ __forceinline__ int min8of(const int* f) {
    const int4 a = *(const int4*)f;
    const int4 b = *(const int4*)(f + 4);
    return imin2(imin2(imin2(a.x, a.y), imin2(a.z, a.w)),
                 imin2(imin2(b.x, b.y), imin2(b.z, b.w)));
}

// Fused slow-path spin: both conditions in ONE poll round, two polls per sleep,
// spinner demoted to prio 0 so chain-critical waves win issue arbitration.
#define SPIN_FUSED(F0, F1, C0, C1)                                              \
    do {                                                                        \
        __builtin_amdgcn_s_setprio(0);                                          \
        for (;;) {                                                              \
            asm volatile("" ::: "memory");                                      \
            if ((min4of(F0) >= (C0)) & (min8of(F1) >= (C1))) break;             \
            asm volatile("" ::: "memory");                                      \
            if ((min4of(F0) >= (C0)) & (min8of(F1) >= (C1))) break;             \
            __builtin_amdgcn_s_sleep(1);                                        \
        }                                                                       \
        __builtin_amdgcn_s_setprio(1);                                          \
    } while (0)

__global__ __launch_bounds__(768, 3)
void lstm_1t_kernel(const float* __restrict__ x,
                    const float* __restrict__ Wih0, const float* __restrict__ Whh0,
                    const float* __restrict__ bih0, const float* __restrict__ bhh0,
                    const float* __restrict__ Wih1, const float* __restrict__ Whh1,
                    const float* __restrict__ bih1, const float* __restrict__ bhh1,
                    const float* __restrict__ Wfc,  const float* __restrict__ bfc,
                    float* __restrict__ out)
{
    __shared__ float xbuf[NB][XP];                   // 33 KB
    __shared__ unsigned short h0r[8][NB][64];        // 16 KB ring, slot t&7
    __shared__ unsigned short h1r[2][NB][64];        // 4 KB ring, slot t&1
    __shared__ float h1fin[HH][NB + 1];              // 4.25 KB
    __shared__ __align__(16) int f0[4];              // L0 wave progress flags
    __shared__ __align__(16) int f1[8];              // L1 wave progress flags

    const int tid  = threadIdx.x;
    const int wv   = tid >> 6;       // 0..11: 0-3 L0 waves, 4-11 L1 waves
    const int lane = tid & 63;
    const int m    = lane & 15;      // batch col (B/C frag) & A-frag row-in-tile
    const int q    = lane >> 4;      // C-frag unit_local; A/B k-quad
    const int m7   = m & 7;
    const int b0   = blockIdx.x * NB;
    const bool isL0 = (wv < 4);

    // ---- stage x (coalesced float4) ----
    for (int i = tid; i < NB * TT / 4; i += 768) {
        const int b  = i >> 7;
        const int t4 = i & 127;
        *(float4*)&xbuf[b][t4 * 4] = *(const float4*)&x[(size_t)(b0 + b) * TT + t4 * 4];
    }
    // ---- zero rings (h(-1) served by zeroed slots) + flags ----
    for (int i = tid; i < 8 * NB * 64; i += 768) (&h0r[0][0][0])[i] = 0;
    for (int i = tid; i < 2 * NB * 64; i += 768) (&h1r[0][0][0])[i] = 0;
    if (tid < 4) f0[tid] = -1;
    else if (tid < 12) f1[tid - 4] = -1;

    // ---- per-lane read offsets (shorts within one slot = 1024) ----
    int roff[2];
#pragma unroll
    for (int kt = 0; kt < 2; ++kt)
        roff[kt] = m * 64 + (((4 * kt + q) ^ m7) * 8);

    const int gate_m = m & 3;
    const float scA  = (gate_m == 2) ? SC_G : SC_IFO;
    unsigned short* const H0 = &h0r[0][0][0];
    unsigned short* const H1 = &h1r[0][0][0];

    __syncthreads();     // the ONLY barrier before the epilogue

    __builtin_amdgcn_s_setprio(1);   // compute runs at prio 1; spinners drop to 0

    if (isL0) {
        // ===== L0 waves: units [16w,16w+16), 4 unit-major tiles, 8 MFMA =====
        const int w = wv;
        bf16x8 Ah[4][2];                    // [tau][kt] of Whh0 (single-term)
        f32x4 bb0s[4], wx0s[4];
        int woff[4];
#pragma unroll
        for (int tau = 0; tau < 4; ++tau) {
            const int rowA = 64 * gate_m + 16 * w + 4 * tau + (m >> 2);
#pragma unroll
            for (int kt = 0; kt < 2; ++kt)
                build_frag_scaled(&Whh0[rowA * HH + kt * 32 + q * 8], scA, Ah[tau][kt]);
#pragma unroll
            for (int r = 0; r < 4; ++r) {
                const int row = 64 * r + 16 * w + 4 * tau + q;
                const float sc = (r == 2) ? SC_G : SC_IFO;
                bb0s[tau][r] = (bih0[row] + bhh0[row]) * sc;
                wx0s[tau][r] = Wih0[row] * sc;
            }
            const int u = 16 * w + 4 * tau + q;
            woff[tau] = m * 64 + (((u >> 3) ^ m7) * 8) + (u & 7);
        }

        f32x2 cA = {0.f, 0.f}, cB = {0.f, 0.f};

#pragma unroll 1
        for (int t = 0; t < TT; ++t) {
            asm volatile("" ::: "memory");
            const int c0 = t - 1;            // h0(t-1) complete (all 4 L0 waves)
            const int c1 = t - 8;            // slot t&7 consumed by all L1 waves
            // issue flag loads now; hide their latency under the x-projection
            const int rdy = (min4of(f0) >= c0) & (min8of(f1) >= c1);

            const float xv = xbuf[m][t];
            f32x4 a[4];
#pragma unroll
            for (int tau = 0; tau < 4; ++tau) {
#pragma unroll
                for (int r = 0; r < 4; ++r)
                    a[tau][r] = __builtin_fmaf(xv, wx0s[tau][r], bb0s[tau][r]);
            }

            if (!rdy) SPIN_FUSED(f0, f1, c0, c1);
            asm volatile("" ::: "memory");

            const int rs = ((t - 1) & 7) * (NB * 64);
            bf16x8 h0[2];
            h0[0] = *(const bf16x8*)(H0 + rs + roff[0]);
            h0[1] = *(const bf16x8*)(H0 + rs + roff[1]);

#pragma unroll
            for (int tau = 0; tau < 4; ++tau) {
                f32x4 z = {0.f, 0.f, 0.f, 0.f};
                a[tau] = MFMA(Ah[tau][0], h0[0], a[tau]);
                z      = MFMA(Ah[tau][1], h0[1], z);
                a[tau] = a[tau] + z;
            }

            const f32x2 hv0 = cell2(a[0], a[1], &cA);
            const f32x2 hv1 = cell2(a[2], a[3], &cB);

            const int ws = (t & 7) * (NB * 64);
            H0[ws + woff[0]] = f32_to_bf16_rne(hv0[0]);
            H0[ws + woff[1]] = f32_to_bf16_rne(hv0[1]);
            H0[ws + woff[2]] = f32_to_bf16_rne(hv1[0]);
            H0[ws + woff[3]] = f32_to_bf16_rne(hv1[1]);

            asm volatile("s_waitcnt lgkmcnt(0)" ::: "memory");
            if (lane == 0) *(volatile int*)&f0[w] = t;
        }
    } else {
        // ===== L1 waves: units [8u,8u+8), 2 tiles, 8 MFMA =====
        const int uW = wv - 4;
        bf16x8 Ah[2][4];     // [tau][kt]: kt0-1 Wih1 (eats h0), kt2-3 Whh1 (eats h1)
        f32x4 bb1s[2];
        int woff[2], uu[2];
#pragma unroll
        for (int tau = 0; tau < 2; ++tau) {
            const int rowA = 64 * gate_m + 8 * uW + 4 * tau + (m >> 2);
#pragma unroll
            for (int kt = 0; kt < 2; ++kt)
                build_frag_scaled(&Wih1[rowA * HH + kt * 32 + q * 8], scA, Ah[tau][kt]);
#pragma unroll
            for (int kt = 0; kt < 2; ++kt)
                build_frag_scaled(&Whh1[rowA * HH + kt * 32 + q * 8], scA, Ah[tau][2 + kt]);
#pragma unroll
            for (int r = 0; r < 4; ++r) {
                const int row = 64 * r + 8 * uW + 4 * tau + q;
                const float sc = (r == 2) ? SC_G : SC_IFO;
                bb1s[tau][r] = (bih1[row] + bhh1[row]) * sc;
            }
            const int u = 8 * uW + 4 * tau + q;
            uu[tau]   = u;
            woff[tau] = m * 64 + (((u >> 3) ^ m7) * 8) + (u & 7);
        }

        f32x2 c1v = {0.f, 0.f};

#pragma unroll 1
        for (int t = 0; t < TT; ++t) {
            asm volatile("" ::: "memory");
            const int c0 = t;                // h0(t) available (all 4 L0 waves)
            const int c1 = t - 1;            // h1(t-1) complete (all 8 L1 waves)
            if (!((min4of(f0) >= c0) & (min8of(f1) >= c1)))
                SPIN_FUSED(f0, f1, c0, c1);
            asm volatile("" ::: "memory");

            // all 4 fragment reads issued together, one lgkm drain by compiler
            const int rs0 = (t & 7) * (NB * 64);
            const int rs1 = ((t - 1) & 1) * (NB * 64);
            bf16x8 h0[2], h1[2];
            h0[0] = *(const bf16x8*)(H0 + rs0 + roff[0]);
            h0[1] = *(const bf16x8*)(H0 + rs0 + roff[1]);
            h1[0] = *(const bf16x8*)(H1 + rs1 + roff[0]);
            h1[1] = *(const bf16x8*)(H1 + rs1 + roff[1]);

            f32x4 a[2];
#pragma unroll
            for (int tau = 0; tau < 2; ++tau) {
                f32x4 p = bb1s[tau];
                f32x4 s = {0.f, 0.f, 0.f, 0.f};
                p = MFMA(Ah[tau][0], h0[0], p);        // Wih1 . h0(t)
                p = MFMA(Ah[tau][1], h0[1], p);
                s = MFMA(Ah[tau][2], h1[0], s);        // Whh1 . h1(t-1)
                s = MFMA(Ah[tau][3], h1[1], s);
                a[tau] = p + s;
            }

            const f32x2 hv = cell2(a[0], a[1], &c1v);
            if (t == TT - 1) {                  // exact fp32 h1(T-1) for FC
                h1fin[uu[0]][m] = hv[0];
                h1fin[uu[1]][m] = hv[1];
            }
            const int ws = (t & 1) * (NB * 64);
            H1[ws + woff[0]] = f32_to_bf16_rne(hv[0]);
            H1[ws + woff[1]] = f32_to_bf16_rne(hv[1]);

            asm volatile("s_waitcnt lgkmcnt(0)" ::: "memory");
            if (lane == 0) *(volatile int*)&f1[uW] = t;
        }
    }

    __syncthreads();

    // ---- FC epilogue: out[b] = h1(T-1)[b] . Wfc + bfc ----
    if (tid < NB) {
        float sacc = bfc[0];
#pragma unroll
        for (int u = 0; u < HH; ++u) sacc = fmaf(h1fin[u][tid], Wfc[u], sacc);
        out[b0 + tid] = sacc;
    }
}

extern "C" void kernel_launch(void* const* d_in, const int* in_sizes, int n_in,
                              void* d_out, int out_size, void* d_ws, size_t ws_size,
                              hipStream_t stream) {
    const float* x    = (const float*)d_in[0];
    const float* Wih0 = (const float*)d_in[1];
    const float* Whh0 = (const float*)d_in[2];
    const float* bih0 = (const float*)d_in[3];
    const float* bhh0 = (const float*)d_in[4];
    const float* Wih1 = (const float*)d_in[5];
    const float* Whh1 = (const float*)d_in[6];
    const float* bih1 = (const float*)d_in[7];
    const float* bhh1 = (const float*)d_in[8];
    const float* Wfc  = (const float*)d_in[9];
    const float* bfc  = (const float*)d_in[10];

    lstm_1t_kernel<<<dim3(4096 / NB), dim3(768), 0, stream>>>(
        x, Wih0, Whh0, bih0, bhh0, Wih1, Whh1, bih1, bhh1, Wfc, bfc, (float*)d_out);
}

// Round 2
// 487.928 us; speedup vs baseline: 1.0092x; 1.0092x over previous
//
#include <hip/hip_runtime.h>

// LSTMForecaster: B=4096, T=512, D=1, H=64, 2 layers + FC(64->1).
// R18 = R16/R17 structure, REBALANCED: 8 L0 waves x 8 units (was 4 x 16) +
//   L1 h0-side MFMAs hoisted off the h1 recurrence chain.
//   Evidence: R17 (fused waits, setprio, double-poll) neutral -> sync detect
//   is NOT the binding path. R16's MFMA cut paid ~1:1 in issue cycles -> the
//   wall is the serialized per-wave step body on the recurrence chain.
//   Changes:
//     1. 16 waves (8 L0 x 8u, 8 L1 x 8u), 1024 thr. L0 wave body halves:
//        1 cell2 (16 trans, was 32), 4 MFMA (was 8), 8 x-FMA (was 16).
//     2. L1 split waits: f0>=t (normally free, L0 runs <=8 ahead) -> read
//        h0(t) + 2 Wih1 MFMAs BEFORE the binding f1>=t-1 wait; after it only
//        h1-read + 2 dependent MFMAs + cell2 remain on the chain. s-accum
//        folded into MFMA C operand (no final vector add).
//   Everything else identical: single-bf16 weights+h, h0 ring 8 / h1 ring 2,
//   exp2-folded gate scales, packed cells, free-running flag sync.
//   If FAIL/regress: revert to R17 (492us).

#define TT 512
#define HH 64
#define NB 16
#define XP 516

typedef __bf16 bf16_t;
typedef bf16_t bf16x8 __attribute__((ext_vector_type(8)));
typedef float  f32x4  __attribute__((ext_vector_type(4)));
typedef float  f32x2  __attribute__((ext_vector_type(2)));

#define MFMA(A, B, C) __builtin_amdgcn_mfma_f32_16x16x32_bf16((A), (B), (C), 0, 0, 0)
#define RCPF(x) __builtin_amdgcn_rcpf(x)

#if __has_builtin(__builtin_amdgcn_exp2f)
#define EXP2F(x) __builtin_amdgcn_exp2f(x)
#else
__device__ __forceinline__ float EXP2F(float x) {
    float r;
    asm volatile("v_exp_f32 %0, %1" : "=v"(r) : "v"(x));
    return r;
}
#endif

#define SC_IFO (-1.4426950408889634f)   // -log2(e)
#define SC_G   ( 2.8853900817779268f)   // +2*log2(e)

__device__ __forceinline__ unsigned short f32_to_bf16_rne(float f) {
    unsigned int u = __builtin_bit_cast(unsigned int, f);
    unsigned int r = u + 0x7fffu + ((u >> 16) & 1u);
    return (unsigned short)(r >> 16);
}
__device__ __forceinline__ bf16_t bits_to_bf16(unsigned short u) {
    return __builtin_bit_cast(bf16_t, u);
}
// single-term weight frag with per-row scale folded in (RNE)
__device__ __forceinline__ void build_frag_scaled(const float* __restrict__ p, float sc,
                                                  bf16x8& w) {
    const float4 a = *(const float4*)p;
    const float4 b = *(const float4*)(p + 4);
    float v[8] = {a.x, a.y, a.z, a.w, b.x, b.y, b.z, b.w};
#pragma unroll
    for (int jj = 0; jj < 8; ++jj)
        w[jj] = bits_to_bf16(f32_to_bf16_rne(v[jj] * sc));
}

__device__ __forceinline__ f32x2 exp2v(f32x2 v) {
    f32x2 r; r[0] = EXP2F(v[0]); r[1] = EXP2F(v[1]); return r;
}
__device__ __forceinline__ f32x2 rcpv(f32x2 v) {
    f32x2 r; r[0] = RCPF(v[0]); r[1] = RCPF(v[1]); return r;
}
// Two cells on PRE-SCALED gates (is,fs,os scaled -log2e; gs scaled +2log2e).
__device__ __forceinline__ f32x2 cell2(const f32x4 a0, const f32x4 a1, f32x2* c) {
    f32x2 is = {a0[0], a1[0]}, fs = {a0[1], a1[1]};
    f32x2 gs = {a0[2], a1[2]}, os = {a0[3], a1[3]};
    const f32x2 pf = exp2v(fs);
    const f32x2 fg = rcpv(1.0f + pf);
    const f32x2 pi = exp2v(is);
    const f32x2 e2 = exp2v(gs);
    const f32x2 z  = (e2 - 1.0f) * rcpv((1.0f + pi) * (1.0f + e2));
    *c = fg * (*c) + z;
    const f32x2 po  = exp2v(os);
    const f32x2 e2c = exp2v((*c) * SC_G);
    return (e2c - 1.0f) * rcpv((1.0f + po) * (1.0f + e2c));
}

__device__ __forceinline__ int imin2(int a, int b) { return a < b ? a : b; }
__device__ __forceinline__ int min8of(const int* f) {
    const int4 a = *(const int4*)f;
    const int4 b = *(const int4*)(f + 4);
    return imin2(imin2(imin2(a.x, a.y), imin2(a.z, a.w)),
                 imin2(imin2(b.x, b.y), imin2(b.z, b.w)));
}

// Slow-path spins: double poll per sleep, spinner demoted to prio 0.
#define SPIN_BOTH(F0, F1, C0, C1)                                               \
    do {                                                                        \
        __builtin_amdgcn_s_setprio(0);                                          \
        for (;;) {                                                              \
            asm volatile("" ::: "memory");                                      \
            if ((min8of(F0) >= (C0)) & (min8of(F1) >= (C1))) break;             \
            asm volatile("" ::: "memory");                                      \
            if ((min8of(F0) >= (C0)) & (min8of(F1) >= (C1))) break;             \
            __builtin_amdgcn_s_sleep(1);                                        \
        }                                                                       \
        __builtin_amdgcn_s_setprio(1);                                          \
    } while (0)

#define SPIN_ONE(F, C)                                                          \
    do {                                                                        \
        __builtin_amdgcn_s_setprio(0);                                          \
        for (;;) {                                                              \
            asm volatile("" ::: "memory");                                      \
            if (min8of(F) >= (C)) break;                                        \
            asm volatile("" ::: "memory");                                      \
            if (min8of(F) >= (C)) break;                                        \
            __builtin_amdgcn_s_sleep(1);                                        \
        }                                                                       \
        __builtin_amdgcn_s_setprio(1);                                          \
    } while (0)

__global__ __launch_bounds__(1024, 4)
void lstm_1t_kernel(const float* __restrict__ x,
                    const float* __restrict__ Wih0, const float* __restrict__ Whh0,
                    const float* __restrict__ bih0, const float* __restrict__ bhh0,
                    const float* __restrict__ Wih1, const float* __restrict__ Whh1,
                    const float* __restrict__ bih1, const float* __restrict__ bhh1,
                    const float* __restrict__ Wfc,  const float* __restrict__ bfc,
                    float* __restrict__ out)
{
    __shared__ float xbuf[NB][XP];                   // 33 KB
    __shared__ unsigned short h0r[8][NB][64];        // 16 KB ring, slot t&7
    __shared__ unsigned short h1r[2][NB][64];        // 4 KB ring, slot t&1
    __shared__ float h1fin[HH][NB + 1];              // 4.25 KB
    __shared__ __align__(16) int f0[8];              // L0 wave progress flags
    __shared__ __align__(16) int f1[8];              // L1 wave progress flags

    const int tid  = threadIdx.x;
    const int wv   = tid >> 6;       // 0..15: 0-7 L0 waves, 8-15 L1 waves
    const int lane = tid & 63;
    const int m    = lane & 15;      // batch col (B/C frag) & A-frag row-in-tile
    const int q    = lane >> 4;      // C-frag unit_local; A/B k-quad
    const int m7   = m & 7;
    const int b0   = blockIdx.x * NB;
    const bool isL0 = (wv < 8);

    // ---- stage x (coalesced float4) ----
    for (int i = tid; i < NB * TT / 4; i += 1024) {
        const int b  = i >> 7;
        const int t4 = i & 127;
        *(float4*)&xbuf[b][t4 * 4] = *(const float4*)&x[(size_t)(b0 + b) * TT + t4 * 4];
    }
    // ---- zero rings (h(-1) served by zeroed slots) + flags ----
    for (int i = tid; i < 8 * NB * 64; i += 1024) (&h0r[0][0][0])[i] = 0;
    for (int i = tid; i < 2 * NB * 64; i += 1024) (&h1r[0][0][0])[i] = 0;
    if (tid < 8) f0[tid] = -1;
    else if (tid < 16) f1[tid - 8] = -1;

    // ---- per-lane read offsets (shorts within one slot = 1024) ----
    int roff[2];
#pragma unroll
    for (int kt = 0; kt < 2; ++kt)
        roff[kt] = m * 64 + (((4 * kt + q) ^ m7) * 8);

    const int gate_m = m & 3;
    const float scA  = (gate_m == 2) ? SC_G : SC_IFO;
    unsigned short* const H0 = &h0r[0][0][0];
    unsigned short* const H1 = &h1r[0][0][0];

    __syncthreads();     // the ONLY barrier before the epilogue

    __builtin_amdgcn_s_setprio(1);   // compute at prio 1; spinners drop to 0

    if (isL0) {
        // ===== L0 waves: units [8w,8w+8), 2 unit-major tiles, 4 MFMA =====
        const int w = wv;
        bf16x8 Ah[2][2];                    // [tau][kt] of Whh0 (single-term)
        f32x4 bb0s[2], wx0s[2];
        int woff[2];
#pragma unroll
        for (int tau = 0; tau < 2; ++tau) {
            const int rowA = 64 * gate_m + 8 * w + 4 * tau + (m >> 2);
#pragma unroll
            for (int kt = 0; kt < 2; ++kt)
                build_frag_scaled(&Whh0[rowA * HH + kt * 32 + q * 8], scA, Ah[tau][kt]);
#pragma unroll
            for (int r = 0; r < 4; ++r) {
                const int row = 64 * r + 8 * w + 4 * tau + q;
                const float sc = (r == 2) ? SC_G : SC_IFO;
                bb0s[tau][r] = (bih0[row] + bhh0[row]) * sc;
                wx0s[tau][r] = Wih0[row] * sc;
            }
            const int u = 8 * w + 4 * tau + q;
            woff[tau] = m * 64 + (((u >> 3) ^ m7) * 8) + (u & 7);
        }

        f32x2 cA = {0.f, 0.f};

#pragma unroll 1
        for (int t = 0; t < TT; ++t) {
            asm volatile("" ::: "memory");
            const int c0 = t - 1;            // h0(t-1) complete (all 8 L0 waves)
            const int c1 = t - 8;            // slot t&7 consumed by all L1 waves
            // issue flag loads now; hide latency under the x-projection
            const int rdy = (min8of(f0) >= c0) & (min8of(f1) >= c1);

            const float xv = xbuf[m][t];
            f32x4 a[2];
#pragma unroll
            for (int tau = 0; tau < 2; ++tau) {
#pragma unroll
                for (int r = 0; r < 4; ++r)
                    a[tau][r] = __builtin_fmaf(xv, wx0s[tau][r], bb0s[tau][r]);
            }

            if (!rdy) SPIN_BOTH(f0, f1, c0, c1);
            asm volatile("" ::: "memory");

            const int rs = ((t - 1) & 7) * (NB * 64);
            bf16x8 h0[2];
            h0[0] = *(const bf16x8*)(H0 + rs + roff[0]);
            h0[1] = *(const bf16x8*)(H0 + rs + roff[1]);

#pragma unroll
            for (int tau = 0; tau < 2; ++tau) {
                f32x4 z = {0.f, 0.f, 0.f, 0.f};
                a[tau] = MFMA(Ah[tau][0], h0[0], a[tau]);
                z      = MFMA(Ah[tau][1], h0[1], z);
                a[tau] = a[tau] + z;
            }

            const f32x2 hv = cell2(a[0], a[1], &cA);

            const int ws = (t & 7) * (NB * 64);
            H0[ws + woff[0]] = f32_to_bf16_rne(hv[0]);
            H0[ws + woff[1]] = f32_to_bf16_rne(hv[1]);

            asm volatile("s_waitcnt lgkmcnt(0)" ::: "memory");
            if (lane == 0) *(volatile int*)&f0[w] = t;
        }
    } else {
        // ===== L1 waves: units [8u,8u+8), 2 tiles, 8 MFMA =====
        const int uW = wv - 8;
        bf16x8 Ah[2][4];     // [tau][kt]: kt0-1 Wih1 (eats h0), kt2-3 Whh1 (eats h1)
        f32x4 bb1s[2];
        int woff[2], uu[2];
#pragma unroll
        for (int tau = 0; tau < 2; ++tau) {
            const int rowA = 64 * gate_m + 8 * uW + 4 * tau + (m >> 2);
#pragma unroll
            for (int kt = 0; kt < 2; ++kt)
                build_frag_scaled(&Wih1[rowA * HH + kt * 32 + q * 8], scA, Ah[tau][kt]);
#pragma unroll
            for (int kt = 0; kt < 2; ++kt)
                build_frag_scaled(&Whh1[rowA * HH + kt * 32 + q * 8], scA, Ah[tau][2 + kt]);
#pragma unroll
            for (int r = 0; r < 4; ++r) {
                const int row = 64 * r + 8 * uW + 4 * tau + q;
                const float sc = (r == 2) ? SC_G : SC_IFO;
                bb1s[tau][r] = (bih1[row] + bhh1[row]) * sc;
            }
            const int u = 8 * uW + 4 * tau + q;
            uu[tau]   = u;
            woff[tau] = m * 64 + (((u >> 3) ^ m7) * 8) + (u & 7);
        }

        f32x2 c1v = {0.f, 0.f};

#pragma unroll 1
        for (int t = 0; t < TT; ++t) {
            asm volatile("" ::: "memory");
            // ---- h0(t) wait: normally free, L0 runs up to 8 steps ahead ----
            if (min8of(f0) < t) SPIN_ONE(f0, t);
            asm volatile("" ::: "memory");

            // h0-side work OFF the h1 recurrence chain
            const int rs0 = (t & 7) * (NB * 64);
            bf16x8 h0[2];
            h0[0] = *(const bf16x8*)(H0 + rs0 + roff[0]);
            h0[1] = *(const bf16x8*)(H0 + rs0 + roff[1]);

            f32x4 a[2];
#pragma unroll
            for (int tau = 0; tau < 2; ++tau) {
                a[tau] = MFMA(Ah[tau][0], h0[0], bb1s[tau]);   // Wih1 . h0(t)
                a[tau] = MFMA(Ah[tau][1], h0[1], a[tau]);
            }

            // ---- binding wait: h1(t-1) complete (all 8 L1 waves) ----
            if (min8of(f1) < t - 1) SPIN_ONE(f1, t - 1);
            asm volatile("" ::: "memory");

            const int rs1 = ((t - 1) & 1) * (NB * 64);
            bf16x8 h1[2];
            h1[0] = *(const bf16x8*)(H1 + rs1 + roff[0]);
            h1[1] = *(const bf16x8*)(H1 + rs1 + roff[1]);

#pragma unroll
            for (int tau = 0; tau < 2; ++tau) {
                a[tau] = MFMA(Ah[tau][2], h1[0], a[tau]);      // + Whh1 . h1(t-1)
                a[tau] = MFMA(Ah[tau][3], h1[1], a[tau]);
            }

            const f32x2 hv = cell2(a[0], a[1], &c1v);
            if (t == TT - 1) {                  // exact fp32 h1(T-1) for FC
                h1fin[uu[0]][m] = hv[0];
                h1fin[uu[1]][m] = hv[1];
            }
            const int ws = (t & 1) * (NB * 64);
            H1[ws + woff[0]] = f32_to_bf16_rne(hv[0]);
            H1[ws + woff[1]] = f32_to_bf16_rne(hv[1]);

            asm volatile("s_waitcnt lgkmcnt(0)" ::: "memory");
            if (lane == 0) *(volatile int*)&f1[uW] = t;
        }
    }

    __syncthreads();

    // ---- FC epilogue: out[b] = h1(T-1)[b] . Wfc + bfc ----
    if (tid < NB) {
        float sacc = bfc[0];
#pragma unroll
        for (int u = 0; u < HH; ++u) sacc = fmaf(h1fin[u][tid], Wfc[u], sacc);
        out[b0 + tid] = sacc;
    }
}

extern "C" void kernel_launch(void* const* d_in, const int* in_sizes, int n_in,
                              void* d_out, int out_size, void* d_ws, size_t ws_size,
                              hipStream_t stream) {
    const float* x    = (const float*)d_in[0];
    const float* Wih0 = (const float*)d_in[1];
    const float* Whh0 = (const float*)d_in[2];
    const float* bih0 = (const float*)d_in[3];
    const float* bhh0 = (const float*)d_in[4];
    const float* Wih1 = (const float*)d_in[5];
    const float* Whh1 = (const float*)d_in[6];
    const float* bih1 = (const float*)d_in[7];
    const float* bhh1 = (const float*)d_in[8];
    const float* Wfc  = (const float*)d_in[9];
    const float* bfc  = (const float*)d_in[10];

    lstm_1t_kernel<<<dim3(4096 / NB), dim3(1024), 0, stream>>>(
        x, Wih0, Whh0, bih0, bhh0, Wih1, Whh1, bih1, bhh1, Wfc, bfc, (float*)d_out);
}

// Round 3
// 420.092 us; speedup vs baseline: 1.1722x; 1.1615x over previous
//
#include <hip/hip_runtime.h>

// LSTMForecaster: B=4096, T=512, D=1, H=64, 2 layers + FC(64->1).
// R19 = R18 wave layout, SYNC REPLACED: LDS flag polling -> s_barrier lockstep.
//   Evidence: R16-R18 pinned the wall at ~2287 cyc/step regardless of per-wave
//   body size, sync detection, or wave count; VALUBusy rose with waves (spin
//   is elastic filler). Arithmetic: spin polls are 2-4 ds_read_b128/iter x 16
//   waves ~ 2.4x oversubscription of the LDS data-return pipe -> critical h
//   read/write latencies inflate behind poll traffic. Fix: remove ALL polling.
//   One-step skew makes iterations dependency-free across waves:
//     iteration tt: L0 computes h0(tt); L1 computes h1(tt-1) from h0(tt-1)
//     (written last iter) and h1(tt-2). One lgkmcnt(0)+s_barrier per iter,
//     513 iters, zero flags, zero sleeps, no setprio.
//   Everything else identical to R18: 16 waves (8 L0 x 8u, 8 L1 x 8u),
//   single-bf16 weights+h, h0 ring 8 / h1 ring 2, exp2-folded gate scales,
//   packed cells. If regress: revert to R18 (488us).

#define TT 512
#define HH 64
#define NB 16
#define XP 516

typedef __bf16 bf16_t;
typedef bf16_t bf16x8 __attribute__((ext_vector_type(8)));
typedef float  f32x4  __attribute__((ext_vector_type(4)));
typedef float  f32x2  __attribute__((ext_vector_type(2)));

#define MFMA(A, B, C) __builtin_amdgcn_mfma_f32_16x16x32_bf16((A), (B), (C), 0, 0, 0)
#define RCPF(x) __builtin_amdgcn_rcpf(x)

#if __has_builtin(__builtin_amdgcn_exp2f)
#define EXP2F(x) __builtin_amdgcn_exp2f(x)
#else
__device__ __forceinline__ float EXP2F(float x) {
    float r;
    asm volatile("v_exp_f32 %0, %1" : "=v"(r) : "v"(x));
    return r;
}
#endif

#define SC_IFO (-1.4426950408889634f)   // -log2(e)
#define SC_G   ( 2.8853900817779268f)   // +2*log2(e)

__device__ __forceinline__ unsigned short f32_to_bf16_rne(float f) {
    unsigned int u = __builtin_bit_cast(unsigned int, f);
    unsigned int r = u + 0x7fffu + ((u >> 16) & 1u);
    return (unsigned short)(r >> 16);
}
__device__ __forceinline__ bf16_t bits_to_bf16(unsigned short u) {
    return __builtin_bit_cast(bf16_t, u);
}
// single-term weight frag with per-row scale folded in (RNE)
__device__ __forceinline__ void build_frag_scaled(const float* __restrict__ p, float sc,
                                                  bf16x8& w) {
    const float4 a = *(const float4*)p;
    const float4 b = *(const float4*)(p + 4);
    float v[8] = {a.x, a.y, a.z, a.w, b.x, b.y, b.z, b.w};
#pragma unroll
    for (int jj = 0; jj < 8; ++jj)
        w[jj] = bits_to_bf16(f32_to_bf16_rne(v[jj] * sc));
}

__device__ __forceinline__ f32x2 exp2v(f32x2 v) {
    f32x2 r; r[0] = EXP2F(v[0]); r[1] = EXP2F(v[1]); return r;
}
__device__ __forceinline__ f32x2 rcpv(f32x2 v) {
    f32x2 r; r[0] = RCPF(v[0]); r[1] = RCPF(v[1]); return r;
}
// Two cells on PRE-SCALED gates (is,fs,os scaled -log2e; gs scaled +2log2e).
__device__ __forceinline__ f32x2 cell2(const f32x4 a0, const f32x4 a1, f32x2* c) {
    f32x2 is = {a0[0], a1[0]}, fs = {a0[1], a1[1]};
    f32x2 gs = {a0[2], a1[2]}, os = {a0[3], a1[3]};
    const f32x2 pf = exp2v(fs);
    const f32x2 fg = rcpv(1.0f + pf);
    const f32x2 pi = exp2v(is);
    const f32x2 e2 = exp2v(gs);
    const f32x2 z  = (e2 - 1.0f) * rcpv((1.0f + pi) * (1.0f + e2));
    *c = fg * (*c) + z;
    const f32x2 po  = exp2v(os);
    const f32x2 e2c = exp2v((*c) * SC_G);
    return (e2c - 1.0f) * rcpv((1.0f + po) * (1.0f + e2c));
}

// per-iteration lockstep: drain LDS writes, hw barrier, fence the compiler
#define STEP_BARRIER()                                                          \
    do {                                                                        \
        asm volatile("s_waitcnt lgkmcnt(0)" ::: "memory");                      \
        __builtin_amdgcn_s_barrier();                                           \
        asm volatile("" ::: "memory");                                          \
    } while (0)

__global__ __launch_bounds__(1024, 4)
void lstm_1t_kernel(const float* __restrict__ x,
                    const float* __restrict__ Wih0, const float* __restrict__ Whh0,
                    const float* __restrict__ bih0, const float* __restrict__ bhh0,
                    const float* __restrict__ Wih1, const float* __restrict__ Whh1,
                    const float* __restrict__ bih1, const float* __restrict__ bhh1,
                    const float* __restrict__ Wfc,  const float* __restrict__ bfc,
                    float* __restrict__ out)
{
    __shared__ float xbuf[NB][XP];                   // 33 KB
    __shared__ unsigned short h0r[8][NB][64];        // 16 KB ring, slot t&7
    __shared__ unsigned short h1r[2][NB][64];        // 4 KB ring, slot t&1
    __shared__ float h1fin[HH][NB + 1];              // 4.25 KB

    const int tid  = threadIdx.x;
    const int wv   = tid >> 6;       // 0..15: 0-7 L0 waves, 8-15 L1 waves
    const int lane = tid & 63;
    const int m    = lane & 15;      // batch col (B/C frag) & A-frag row-in-tile
    const int q    = lane >> 4;      // C-frag unit_local; A/B k-quad
    const int m7   = m & 7;
    const int b0   = blockIdx.x * NB;
    const bool isL0 = (wv < 8);

    // ---- stage x (coalesced float4) ----
    for (int i = tid; i < NB * TT / 4; i += 1024) {
        const int b  = i >> 7;
        const int t4 = i & 127;
        *(float4*)&xbuf[b][t4 * 4] = *(const float4*)&x[(size_t)(b0 + b) * TT + t4 * 4];
    }
    // ---- zero rings (h(-1)/h(-2) served by zeroed slots) ----
    for (int i = tid; i < 8 * NB * 64; i += 1024) (&h0r[0][0][0])[i] = 0;
    for (int i = tid; i < 2 * NB * 64; i += 1024) (&h1r[0][0][0])[i] = 0;

    // ---- per-lane read offsets (shorts within one slot = 1024) ----
    int roff[2];
#pragma unroll
    for (int kt = 0; kt < 2; ++kt)
        roff[kt] = m * 64 + (((4 * kt + q) ^ m7) * 8);

    const int gate_m = m & 3;
    const float scA  = (gate_m == 2) ? SC_G : SC_IFO;
    unsigned short* const H0 = &h0r[0][0][0];
    unsigned short* const H1 = &h1r[0][0][0];

    __syncthreads();     // staging visible (drains vmcnt too)

    if (isL0) {
        // ===== L0 waves: units [8w,8w+8), 2 unit-major tiles, 4 MFMA =====
        const int w = wv;
        bf16x8 Ah[2][2];                    // [tau][kt] of Whh0 (single-term)
        f32x4 bb0s[2], wx0s[2];
        int woff[2];
#pragma unroll
        for (int tau = 0; tau < 2; ++tau) {
            const int rowA = 64 * gate_m + 8 * w + 4 * tau + (m >> 2);
#pragma unroll
            for (int kt = 0; kt < 2; ++kt)
                build_frag_scaled(&Whh0[rowA * HH + kt * 32 + q * 8], scA, Ah[tau][kt]);
#pragma unroll
            for (int r = 0; r < 4; ++r) {
                const int row = 64 * r + 8 * w + 4 * tau + q;
                const float sc = (r == 2) ? SC_G : SC_IFO;
                bb0s[tau][r] = (bih0[row] + bhh0[row]) * sc;
                wx0s[tau][r] = Wih0[row] * sc;
            }
            const int u = 8 * w + 4 * tau + q;
            woff[tau] = m * 64 + (((u >> 3) ^ m7) * 8) + (u & 7);
        }

        f32x2 cA = {0.f, 0.f};

#pragma unroll 1
        for (int tt = 0; tt <= TT; ++tt) {
            if (tt < TT) {
                // h0(tt-1) guaranteed by last iteration's barrier (tt=0: zeroed slot 7)
                const int rs = ((tt - 1) & 7) * (NB * 64);
                bf16x8 h0[2];
                h0[0] = *(const bf16x8*)(H0 + rs + roff[0]);
                h0[1] = *(const bf16x8*)(H0 + rs + roff[1]);

                const float xv = xbuf[m][tt];
                f32x4 a[2];
#pragma unroll
                for (int tau = 0; tau < 2; ++tau) {
#pragma unroll
                    for (int r = 0; r < 4; ++r)
                        a[tau][r] = __builtin_fmaf(xv, wx0s[tau][r], bb0s[tau][r]);
                }

#pragma unroll
                for (int tau = 0; tau < 2; ++tau) {
                    f32x4 z = {0.f, 0.f, 0.f, 0.f};
                    a[tau] = MFMA(Ah[tau][0], h0[0], a[tau]);
                    z      = MFMA(Ah[tau][1], h0[1], z);
                    a[tau] = a[tau] + z;
                }

                const f32x2 hv = cell2(a[0], a[1], &cA);

                const int ws = (tt & 7) * (NB * 64);
                H0[ws + woff[0]] = f32_to_bf16_rne(hv[0]);
                H0[ws + woff[1]] = f32_to_bf16_rne(hv[1]);
            }
            STEP_BARRIER();
        }
    } else {
        // ===== L1 waves: units [8u,8u+8), skewed one step: iter tt computes h1(tt-1) =====
        const int uW = wv - 8;
        bf16x8 Ah[2][4];     // [tau][kt]: kt0-1 Wih1 (eats h0), kt2-3 Whh1 (eats h1)
        f32x4 bb1s[2];
        int woff[2], uu[2];
#pragma unroll
        for (int tau = 0; tau < 2; ++tau) {
            const int rowA = 64 * gate_m + 8 * uW + 4 * tau + (m >> 2);
#pragma unroll
            for (int kt = 0; kt < 2; ++kt)
                build_frag_scaled(&Wih1[rowA * HH + kt * 32 + q * 8], scA, Ah[tau][kt]);
#pragma unroll
            for (int kt = 0; kt < 2; ++kt)
                build_frag_scaled(&Whh1[rowA * HH + kt * 32 + q * 8], scA, Ah[tau][2 + kt]);
#pragma unroll
            for (int r = 0; r < 4; ++r) {
                const int row = 64 * r + 8 * uW + 4 * tau + q;
                const float sc = (r == 2) ? SC_G : SC_IFO;
                bb1s[tau][r] = (bih1[row] + bhh1[row]) * sc;
            }
            const int u = 8 * uW + 4 * tau + q;
            uu[tau]   = u;
            woff[tau] = m * 64 + (((u >> 3) ^ m7) * 8) + (u & 7);
        }

        f32x2 c1v = {0.f, 0.f};

#pragma unroll 1
        for (int tt = 0; tt <= TT; ++tt) {
            if (tt >= 1) {
                const int tm = tt - 1;          // computing h1(tm)
                // h0(tm): written by L0 in iteration tm (>=1 barrier ago)
                // h1(tm-1): written by L1 in iteration tm (1 barrier ago); tm=0 -> zeroed
                const int rs0 = (tm & 7) * (NB * 64);
                const int rs1 = ((tm - 1) & 1) * (NB * 64);
                bf16x8 h0[2], h1[2];
                h0[0] = *(const bf16x8*)(H0 + rs0 + roff[0]);
                h0[1] = *(const bf16x8*)(H0 + rs0 + roff[1]);
                h1[0] = *(const bf16x8*)(H1 + rs1 + roff[0]);
                h1[1] = *(const bf16x8*)(H1 + rs1 + roff[1]);

                f32x4 a[2];
#pragma unroll
                for (int tau = 0; tau < 2; ++tau) {
                    a[tau] = MFMA(Ah[tau][0], h0[0], bb1s[tau]);   // Wih1 . h0(tm)
                    a[tau] = MFMA(Ah[tau][1], h0[1], a[tau]);
                    a[tau] = MFMA(Ah[tau][2], h1[0], a[tau]);      // + Whh1 . h1(tm-1)
                    a[tau] = MFMA(Ah[tau][3], h1[1], a[tau]);
                }

                const f32x2 hv = cell2(a[0], a[1], &c1v);
                if (tm == TT - 1) {                 // exact fp32 h1(T-1) for FC
                    h1fin[uu[0]][m] = hv[0];
                    h1fin[uu[1]][m] = hv[1];
                }
                const int ws = (tm & 1) * (NB * 64);
                H1[ws + woff[0]] = f32_to_bf16_rne(hv[0]);
                H1[ws + woff[1]] = f32_to_bf16_rne(hv[1]);
            }
            STEP_BARRIER();
        }
    }

    __syncthreads();

    // ---- FC epilogue: out[b] = h1(T-1)[b] . Wfc + bfc ----
    if (tid < NB) {
        float sacc = bfc[0];
#pragma unroll
        for (int u = 0; u < HH; ++u) sacc = fmaf(h1fin[u][tid], Wfc[u], sacc);
        out[b0 + tid] = sacc;
    }
}

extern "C" void kernel_launch(void* const* d_in, const int* in_sizes, int n_in,
                              void* d_out, int out_size, void* d_ws, size_t ws_size,
                              hipStream_t stream) {
    const float* x    = (const float*)d_in[0];
    const float* Wih0 = (const float*)d_in[1];
    const float* Whh0 = (const float*)d_in[2];
    const float* bih0 = (const float*)d_in[3];
    const float* bhh0 = (const float*)d_in[4];
    const float* Wih1 = (const float*)d_in[5];
    const float* Whh1 = (const float*)d_in[6];
    const float* bih1 = (const float*)d_in[7];
    const float* bhh1 = (const float*)d_in[8];
    const float* Wfc  = (const float*)d_in[9];
    const float* bfc  = (const float*)d_in[10];

    lstm_1t_kernel<<<dim3(4096 / NB), dim3(1024), 0, stream>>>(
        x, Wih0, Whh0, bih0, bhh0, Wih1, Whh1, bih1, bhh1, Wfc, bfc, (float*)d_out);
}